// Round 11
// baseline (171.239 us; speedup 1.0000x reference)
//
#include <hip/hip_runtime.h>
#include <math.h>

// Problem constants
constexpr int B = 2, C = 256, H = 56, W = 96;
constexpr int HW = H * W;
constexpr int RADIUS = 4;

// int8 quantization: scale 127/6 for both fmaps; dots rescaled at the end.
#define SQ 21.166666f                    // 127/6
constexpr float SCL = 36.0f / (127.0f * 127.0f * 16.0f);  // 1/(SQ^2 * sqrt(C))

// Workspace layout (byte offsets, all 16B-aligned)
constexpr size_t F1T_B = 0;                                   // i8 [B,HW,C]
constexpr size_t L0_B  = (size_t)B * HW * C;                  // i8 [B,HW,C]
constexpr size_t L1_B  = L0_B + (size_t)B * HW * C;           // i8 [B,28*48,C]
constexpr size_t L2_B  = L1_B + (size_t)B * 28 * 48 * C;      // i8 [B,14*24,C]
constexpr size_t L3_B  = L2_B + (size_t)B * 14 * 24 * C;      // i8 [B,7*12,C]
constexpr size_t OUT0_ELEMS = (size_t)B * 324 * HW;

static __device__ __forceinline__ int dot4acc(int a, int b, int c) {
#if __has_builtin(__builtin_amdgcn_sdot4)
    return __builtin_amdgcn_sdot4(a, b, c, false);
#else
    c += (int)(char)(a) * (int)(char)(b);
    c += (int)(char)(a >> 8) * (int)(char)(b >> 8);
    c += (int)(char)(a >> 16) * (int)(char)(b >> 16);
    c += (int)(char)(a >> 24) * (int)(char)(b >> 24);
    return c;
#endif
}

static __device__ __forceinline__ unsigned short pack_i8x2(float a, float b) {
    int ia = (int)rintf(a); ia = ia < -127 ? -127 : (ia > 127 ? 127 : ia);
    int ib = (int)rintf(b); ib = ib < -127 ? -127 : (ib > 127 ? 127 : ib);
    return (unsigned short)((ia & 0xFF) | ((ib & 0xFF) << 8));
}

// async global->LDS, 16 B per lane. Dest is WAVE-UNIFORM base; HW adds lane*16.
static __device__ __forceinline__ void gload16(const char* g, char* l, int lane) {
#if __has_builtin(__builtin_amdgcn_global_load_lds)
    __builtin_amdgcn_global_load_lds(
        (const __attribute__((address_space(1))) void*)g,
        (__attribute__((address_space(3))) void*)l, 16, 0, 0);
#else
    *(int4*)(l + lane * 16) = *(const int4*)g;
#endif
}

#define WAITVM4() asm volatile("s_waitcnt vmcnt(4)" ::: "memory")
#define WAITVM0() asm volatile("s_waitcnt vmcnt(0)" ::: "memory")

// ---------------------------------------------------------------------------
// prep_kernel: fused {fp32->i8 channel-last transpose of fmap1/fmap2} and
// {convex upsample} (independent inputs). [r4-verified]
constexpr int TP_BLOCKS = (HW / 32) * (C / 64) * 2 * B;   // 2688
constexpr int CU_BLOCKS = B * H * 8;                      // 896
__global__ __launch_bounds__(256) void prep_kernel(
    const float* __restrict__ fmap1, const float* __restrict__ fmap2,
    const float* __restrict__ flow, const float* __restrict__ mask,
    char* __restrict__ ws, float* __restrict__ out1) {
    __shared__ float smem[72 * 96 + 2 * 3 * 98];
    int bid = blockIdx.x;
    int tid = threadIdx.x;

    if (bid < TP_BLOCKS) {
        float (*tile)[33] = (float(*)[33])smem;   // 64 x 33 floats
        int zi = bid / 672;                       // 672 = 168*4
        int rem = bid % 672;
        int by = rem / 168, bx = rem % 168;
        int b = zi & 1, m = zi >> 1;              // m=0: fmap1, m=1: fmap2
        const float* src = m ? fmap2 : fmap1;
        unsigned short* dst = (unsigned short*)(ws + (m ? L0_B : F1T_B));
        int c0 = by * 64, q0 = bx * 32;
        int tx = tid & 31, ty = tid >> 5;
#pragma unroll
        for (int r = 0; r < 8; ++r) {
            int cl = ty + r * 8;
            tile[cl][tx] = src[((size_t)(b * C + c0 + cl)) * HW + q0 + tx];
        }
        __syncthreads();
#pragma unroll
        for (int r = 0; r < 4; ++r) {
            int pl = ty + r * 8;
            dst[((size_t)b * HW + q0 + pl) * 128 + (c0 >> 1) + tx] =
                pack_i8x2(tile[2 * tx][pl] * SQ, tile[2 * tx + 1][pl] * SQ);
        }
        return;
    }

    // ---- convex upsample ----
    float* msk = smem;               // 72*96
    float* fst = smem + 72 * 96;     // 2*3*98
    int cb = bid - TP_BLOCKS;
    int i = cb & 7;
    int r = cb >> 3;
    int h = r % H;
    int b = r / H;

    for (int idx = tid; idx < 72 * 96; idx += 256) {
        int row = idx / 96, wc = idx - row * 96;
        int k = row >> 3, j = row & 7;
        int gl = k * 64 + i * 8 + j;
        msk[idx] = mask[((size_t)(b * 576 + gl)) * HW + h * W + wc];
    }
    for (int idx = tid; idx < 588; idx += 256) {
        int ch = idx / 294;
        int rem2 = idx - ch * 294;
        int rr = rem2 / 98;
        int xw = rem2 - rr * 98;
        int hh = h + rr - 1, ww = xw - 1;
        float v = 0.f;
        if (hh >= 0 && hh < H && ww >= 0 && ww < W)
            v = 8.0f * flow[((size_t)(b * 2 + ch)) * HW + hh * W + ww];
        fst[idx] = v;
    }
    __syncthreads();

#pragma unroll
    for (int rr = 0; rr < 3; ++rr) {
        int col = tid + rr * 256;    // 0..767
        int w = col >> 3, j = col & 7;
        float m[9], mx = -1e30f;
#pragma unroll
        for (int k = 0; k < 9; ++k) {
            m[k] = msk[(k * 8 + j) * 96 + w];
            mx = fmaxf(mx, m[k]);
        }
        float sum = 0.f;
#pragma unroll
        for (int k = 0; k < 9; ++k) {
            m[k] = __expf(m[k] - mx);
            sum += m[k];
        }
        float inv = 1.0f / sum;
        float a0 = 0.f, a1 = 0.f;
#pragma unroll
        for (int k = 0; k < 9; ++k) {
            int ki = k / 3, kj = k - ki * 3;
            float wgt = m[k] * inv;
            a0 = fmaf(wgt, fst[0 * 294 + ki * 98 + w + kj], a0);
            a1 = fmaf(wgt, fst[1 * 294 + ki * 98 + w + kj], a1);
        }
        size_t row8 = (size_t)8 * h + i;
        out1[((size_t)(b * 2 + 0) * 448 + row8) * 768 + col] = a0;
        out1[((size_t)(b * 2 + 1) * 448 + row8) * 768 + col] = a1;
    }
}

// ---------------------------------------------------------------------------
// build_pools: pyramid levels 1..3 from i8 L0; one thread per channel PAIR.
constexpr int NP1 = B * 28 * 48 * C / 2;   // 344,064
constexpr int NP2 = B * 14 * 24 * C / 2;   //  86,016
constexpr int NP3 = B * 7 * 12 * C / 2;    //  21,504

template <int S>
static __device__ __forceinline__ void pool_accum(const unsigned short* src,
                                                  int& sx, int& sy) {
#pragma unroll
    for (int dy = 0; dy < S; ++dy)
#pragma unroll
        for (int dx = 0; dx < S; ++dx) {
            unsigned short v = src[(size_t)dy * (W * 128) + dx * 128];
            sx += (int)(char)(v & 0xFF);
            sy += (int)(char)(v >> 8);
        }
}

__global__ __launch_bounds__(256) void build_pools(char* __restrict__ ws) {
    const unsigned short* L0p = (const unsigned short*)(ws + L0_B);
    int t = blockIdx.x * 256 + threadIdx.x;
    int l, tl;
    if (t < NP1)             { l = 1; tl = t; }
    else if (t < NP1 + NP2)  { l = 2; tl = t - NP1; }
    else                     { l = 3; tl = t - NP1 - NP2; }
    int Wo = W >> l, Ho = H >> l, S = 1 << l;
    int c2 = tl & 127;
    int r = tl >> 7;
    int x = r % Wo; r /= Wo;
    int y = r % Ho;
    int b = r / Ho;
    const unsigned short* src =
        L0p + ((size_t)(b * H + y * S) * W + x * S) * 128 + c2;
    int sx = 0, sy = 0;
    if (l == 1)      pool_accum<2>(src, sx, sy);
    else if (l == 2) pool_accum<4>(src, sx, sy);
    else             pool_accum<8>(src, sx, sy);
    float inv = 1.0f / (S * S);
    unsigned short* dst = (unsigned short*)(ws + (l == 1 ? L1_B : (l == 2 ? L2_B : L3_B)));
    dst[tl] = pack_i8x2((float)sx * inv, (float)sy * inv);
}

// ---------------------------------------------------------------------------
// corr_fused: block = (one pyramid level, 16 consecutive queries), 4 waves x
// 4 queries. ASYNC PIPELINE: per iteration, 4x global_load_lds stage the next
// 16 positions' 4 KB into a wave-private LDS double buffer (loads hold NO
// VGPRs -> compiler cannot serialize them for register economy), counted
// s_waitcnt vmcnt(4) (never 0 mid-loop), then ds_read_b128 + 16 sdot4 on the
// current buffer. No __syncthreads in the loop (wave-private buffers).
constexpr int QB = 672;                    // B*HW/16 query-groups per level
__global__ __launch_bounds__(256, 4) void corr_fused(
    const float* __restrict__ coords, const char* __restrict__ ws,
    float* __restrict__ out0) {
    __shared__ float Dsh[16][101];   // stride 101: conflict-free reads
    __shared__ float Wxy[16][2];
    __shared__ __align__(16) char stage[4][2][4096];   // [wave][buf][16pos*256B]

    int tid = threadIdx.x;
    int wave = tid >> 6;
    int lane = tid & 63;
    int v = lane & 3;              // 16-B sub-chunk within each 64-B line
    int grp = lane >> 2;           // position index within iteration, 0..15

    int bid = blockIdx.x;
    int l = bid / QB;              // level: blocks grouped by level
    int qb = bid - l * QB;
    int g0 = qb * 16;              // 16 consecutive flat queries
    int b = g0 / HW;
    int hw0 = g0 - b * HW;

    int Hl = H >> l, Wl = W >> l;
    int Wlm1 = Wl - 1, Hlm1 = Hl - 1;
    size_t off = (l == 0 ? L0_B : (l == 1 ? L1_B : (l == 2 ? L2_B : L3_B)));
    const char* base8 = ws + off + (size_t)b * Hl * Wl * C;
    float scale = (l == 0 ? 1.0f : (l == 1 ? 0.5f : (l == 2 ? 0.25f : 0.125f)));

    // p = it*16 + grp; (xo,yo) = (p%10, p/10); advance p+=16: xo+=6 mod 10.
    int xo0 = grp < 10 ? grp : grp - 10;
    int yo0 = grp < 10 ? 0 : 1;

    const char* f1b = ws + F1T_B;
    char* st0 = &stage[wave][0][0];
    char* st1 = &stage[wave][1][0];

#pragma unroll 1
    for (int qi = 0; qi < 4; ++qi) {
        int wq = wave * 4 + qi;          // query slot 0..15
        int g = g0 + wq;
        // A chunks at k*64 + v*16 (match column partition; exact repartition)
        const char* ab = f1b + (size_t)g * C + (v << 4);
        int4 A0 = *(const int4*)(ab);
        int4 A1 = *(const int4*)(ab + 64);
        int4 A2 = *(const int4*)(ab + 128);
        int4 A3 = *(const int4*)(ab + 192);

        float cx = coords[(size_t)(b * 2 + 0) * HW + hw0 + wq];
        float cy = coords[(size_t)(b * 2 + 1) * HW + hw0 + wq];
        float fx = cx * scale, fy = cy * scale;
        float fxf = floorf(fx), fyf = floorf(fy);
        float wx = fx - fxf, wy = fy - fyf;
        int ix = (int)fxf, iy = (int)fyf;
        if (lane == 0) { Wxy[wq][0] = wx; Wxy[wq][1] = wy; }

        // Precompute clamped per-lane source offsets + validity bits
        int offv[7];
        unsigned vmask = 0;
        {
            int xo = xo0, yo = yo0;
#pragma unroll
            for (int it = 0; it < 7; ++it) {
                int x = ix - RADIUS + xo;
                int y = iy - RADIUS + yo;
                if (((unsigned)x < (unsigned)Wl) & ((unsigned)y < (unsigned)Hl))
                    vmask |= 1u << it;
                int xc = min(max(x, 0), Wlm1);
                int yc = min(max(y, 0), Hlm1);
                offv[it] = ((yc * Wl + xc) << 8) + (v << 4);
                xo += 6;
                int cr = xo >= 10;
                xo -= cr ? 10 : 0;
                yo += 1 + cr;
            }
        }

        // prologue: stage it=0 into buf0 (4 x 1 KB, no VGPR cost)
        {
            const char* s = base8 + offv[0];
            gload16(s,       st0,        lane);
            gload16(s + 64,  st0 + 1024, lane);
            gload16(s + 128, st0 + 2048, lane);
            gload16(s + 192, st0 + 3072, lane);
        }

#pragma unroll
        for (int it = 0; it < 7; ++it) {
            char* cur = (it & 1) ? st1 : st0;
            if (it < 6) {
                char* nxt = (it & 1) ? st0 : st1;
                const char* s = base8 + offv[it + 1];
                gload16(s,       nxt,        lane);
                gload16(s + 64,  nxt + 1024, lane);
                gload16(s + 128, nxt + 2048, lane);
                gload16(s + 192, nxt + 3072, lane);
                WAITVM4();            // cur's 4 loads done; next 4 in flight
            } else {
                WAITVM0();            // drain last buffer
            }
            const char* sb = cur + grp * 64 + (v << 4);
            int4 c0 = *(const int4*)(sb);
            int4 c1 = *(const int4*)(sb + 1024);
            int4 c2 = *(const int4*)(sb + 2048);
            int4 c3 = *(const int4*)(sb + 3072);
            int s0 = 0, s1 = 0, s2 = 0, s3 = 0;
            s0 = dot4acc(c0.x, A0.x, s0); s1 = dot4acc(c0.y, A0.y, s1);
            s2 = dot4acc(c0.z, A0.z, s2); s3 = dot4acc(c0.w, A0.w, s3);
            s0 = dot4acc(c1.x, A1.x, s0); s1 = dot4acc(c1.y, A1.y, s1);
            s2 = dot4acc(c1.z, A1.z, s2); s3 = dot4acc(c1.w, A1.w, s3);
            s0 = dot4acc(c2.x, A2.x, s0); s1 = dot4acc(c2.y, A2.y, s1);
            s2 = dot4acc(c2.z, A2.z, s2); s3 = dot4acc(c2.w, A2.w, s3);
            s0 = dot4acc(c3.x, A3.x, s0); s1 = dot4acc(c3.y, A3.y, s1);
            s2 = dot4acc(c3.z, A3.z, s2); s3 = dot4acc(c3.w, A3.w, s3);
            int s = (s0 + s1) + (s2 + s3);
            s = ((vmask >> it) & 1) ? s : 0;
            s += __shfl_xor(s, 1);
            s += __shfl_xor(s, 2);
            bool live = (it < 6) | (grp < 4);      // p < 100
            if (v == 0 && live) Dsh[wq][it * 16 + grp] = (float)s * SCL;
        }
    }
    __syncthreads();

    // Bilinear combine + [B,324,HW] f32 write: 16 q x 4 B = full 64-B lines
    int chbase = l * 81;
    for (int o = tid; o < 81 * 16; o += 256) {
        int q = o & 15, ch = o >> 4;
        int xo = ch / 9;                       // x-offset slow (reference quirk)
        int yo = ch - xo * 9;                  // y-offset fast
        float wxv = Wxy[q][0], wyv = Wxy[q][1];
        const float* D = Dsh[q];
        float v00 = D[yo * 10 + xo];
        float v01 = D[yo * 10 + xo + 1];
        float v10 = D[yo * 10 + xo + 10];
        float v11 = D[yo * 10 + xo + 11];
        float res = (1.f - wyv) * ((1.f - wxv) * v00 + wxv * v01)
                  +        wyv  * ((1.f - wxv) * v10 + wxv * v11);
        out0[((size_t)(b * 324 + chbase + ch)) * HW + hw0 + q] = res;
    }
}

extern "C" void kernel_launch(void* const* d_in, const int* in_sizes, int n_in,
                              void* d_out, int out_size, void* d_ws, size_t ws_size,
                              hipStream_t stream) {
    const float* fmap1  = (const float*)d_in[0];
    const float* fmap2  = (const float*)d_in[1];
    const float* coords = (const float*)d_in[2];
    const float* flow   = (const float*)d_in[3];
    const float* maskp  = (const float*)d_in[4];
    float* out = (float*)d_out;
    char* ws = (char*)d_ws;

    prep_kernel<<<TP_BLOCKS + CU_BLOCKS, 256, 0, stream>>>(
        fmap1, fmap2, flow, maskp, ws, out + OUT0_ELEMS);
    build_pools<<<(NP1 + NP2 + NP3) / 256, 256, 0, stream>>>(ws);
    corr_fused<<<4 * QB, 256, 0, stream>>>(coords, ws, out);
}

// Round 12
// 150.582 us; speedup vs baseline: 1.1372x; 1.1372x over previous
//
#include <hip/hip_runtime.h>
#include <math.h>

// Problem constants
constexpr int B = 2, C = 256, H = 56, W = 96;
constexpr int HW = H * W;
constexpr int RADIUS = 4;

// int8 quantization: scale 127/6 for both fmaps; dots rescaled at the end.
#define SQ 21.166666f                    // 127/6
constexpr float SCL = 36.0f / (127.0f * 127.0f * 16.0f);  // 1/(SQ^2 * sqrt(C))

// Workspace layout (byte offsets, all 16B-aligned)
constexpr size_t F1T_B = 0;                                   // i8 [B,HW,C]
constexpr size_t L0_B  = (size_t)B * HW * C;                  // i8 [B,HW,C]
constexpr size_t L1_B  = L0_B + (size_t)B * HW * C;           // i8 [B,28*48,C]
constexpr size_t L2_B  = L1_B + (size_t)B * 28 * 48 * C;      // i8 [B,14*24,C]
constexpr size_t L3_B  = L2_B + (size_t)B * 14 * 24 * C;      // i8 [B,7*12,C]
constexpr size_t OUT0_ELEMS = (size_t)B * 324 * HW;

static __device__ __forceinline__ int dot4acc(int a, int b, int c) {
#if __has_builtin(__builtin_amdgcn_sdot4)
    return __builtin_amdgcn_sdot4(a, b, c, false);
#else
    c += (int)(char)(a) * (int)(char)(b);
    c += (int)(char)(a >> 8) * (int)(char)(b >> 8);
    c += (int)(char)(a >> 16) * (int)(char)(b >> 16);
    c += (int)(char)(a >> 24) * (int)(char)(b >> 24);
    return c;
#endif
}

static __device__ __forceinline__ unsigned short pack_i8x2(float a, float b) {
    int ia = (int)rintf(a); ia = ia < -127 ? -127 : (ia > 127 ? 127 : ia);
    int ib = (int)rintf(b); ib = ib < -127 ? -127 : (ib > 127 ? 127 : ib);
    return (unsigned short)((ia & 0xFF) | ((ib & 0xFF) << 8));
}

// ---------------------------------------------------------------------------
// prep_kernel: fused {fp32->i8 channel-last transpose of fmap1/fmap2} and
// {convex upsample} (independent inputs). [r4-verified]
constexpr int TP_BLOCKS = (HW / 32) * (C / 64) * 2 * B;   // 2688
constexpr int CU_BLOCKS = B * H * 8;                      // 896
__global__ __launch_bounds__(256) void prep_kernel(
    const float* __restrict__ fmap1, const float* __restrict__ fmap2,
    const float* __restrict__ flow, const float* __restrict__ mask,
    char* __restrict__ ws, float* __restrict__ out1) {
    __shared__ float smem[72 * 96 + 2 * 3 * 98];
    int bid = blockIdx.x;
    int tid = threadIdx.x;

    if (bid < TP_BLOCKS) {
        float (*tile)[33] = (float(*)[33])smem;   // 64 x 33 floats
        int zi = bid / 672;                       // 672 = 168*4
        int rem = bid % 672;
        int by = rem / 168, bx = rem % 168;
        int b = zi & 1, m = zi >> 1;              // m=0: fmap1, m=1: fmap2
        const float* src = m ? fmap2 : fmap1;
        unsigned short* dst = (unsigned short*)(ws + (m ? L0_B : F1T_B));
        int c0 = by * 64, q0 = bx * 32;
        int tx = tid & 31, ty = tid >> 5;
#pragma unroll
        for (int r = 0; r < 8; ++r) {
            int cl = ty + r * 8;
            tile[cl][tx] = src[((size_t)(b * C + c0 + cl)) * HW + q0 + tx];
        }
        __syncthreads();
#pragma unroll
        for (int r = 0; r < 4; ++r) {
            int pl = ty + r * 8;
            dst[((size_t)b * HW + q0 + pl) * 128 + (c0 >> 1) + tx] =
                pack_i8x2(tile[2 * tx][pl] * SQ, tile[2 * tx + 1][pl] * SQ);
        }
        return;
    }

    // ---- convex upsample ----
    float* msk = smem;               // 72*96
    float* fst = smem + 72 * 96;     // 2*3*98
    int cb = bid - TP_BLOCKS;
    int i = cb & 7;
    int r = cb >> 3;
    int h = r % H;
    int b = r / H;

    for (int idx = tid; idx < 72 * 96; idx += 256) {
        int row = idx / 96, wc = idx - row * 96;
        int k = row >> 3, j = row & 7;
        int gl = k * 64 + i * 8 + j;
        msk[idx] = mask[((size_t)(b * 576 + gl)) * HW + h * W + wc];
    }
    for (int idx = tid; idx < 588; idx += 256) {
        int ch = idx / 294;
        int rem2 = idx - ch * 294;
        int rr = rem2 / 98;
        int xw = rem2 - rr * 98;
        int hh = h + rr - 1, ww = xw - 1;
        float v = 0.f;
        if (hh >= 0 && hh < H && ww >= 0 && ww < W)
            v = 8.0f * flow[((size_t)(b * 2 + ch)) * HW + hh * W + ww];
        fst[idx] = v;
    }
    __syncthreads();

#pragma unroll
    for (int rr = 0; rr < 3; ++rr) {
        int col = tid + rr * 256;    // 0..767
        int w = col >> 3, j = col & 7;
        float m[9], mx = -1e30f;
#pragma unroll
        for (int k = 0; k < 9; ++k) {
            m[k] = msk[(k * 8 + j) * 96 + w];
            mx = fmaxf(mx, m[k]);
        }
        float sum = 0.f;
#pragma unroll
        for (int k = 0; k < 9; ++k) {
            m[k] = __expf(m[k] - mx);
            sum += m[k];
        }
        float inv = 1.0f / sum;
        float a0 = 0.f, a1 = 0.f;
#pragma unroll
        for (int k = 0; k < 9; ++k) {
            int ki = k / 3, kj = k - ki * 3;
            float wgt = m[k] * inv;
            a0 = fmaf(wgt, fst[0 * 294 + ki * 98 + w + kj], a0);
            a1 = fmaf(wgt, fst[1 * 294 + ki * 98 + w + kj], a1);
        }
        size_t row8 = (size_t)8 * h + i;
        out1[((size_t)(b * 2 + 0) * 448 + row8) * 768 + col] = a0;
        out1[((size_t)(b * 2 + 1) * 448 + row8) * 768 + col] = a1;
    }
}

// ---------------------------------------------------------------------------
// build_pools: pyramid levels 1..3 from i8 L0; one thread per channel PAIR.
// [r4-verified; ~3x faster than the fp32-pool variant]
constexpr int NP1 = B * 28 * 48 * C / 2;   // 344,064
constexpr int NP2 = B * 14 * 24 * C / 2;   //  86,016
constexpr int NP3 = B * 7 * 12 * C / 2;    //  21,504

template <int S>
static __device__ __forceinline__ void pool_accum(const unsigned short* src,
                                                  int& sx, int& sy) {
#pragma unroll
    for (int dy = 0; dy < S; ++dy)
#pragma unroll
        for (int dx = 0; dx < S; ++dx) {
            unsigned short v = src[(size_t)dy * (W * 128) + dx * 128];
            sx += (int)(char)(v & 0xFF);
            sy += (int)(char)(v >> 8);
        }
}

__global__ __launch_bounds__(256) void build_pools(char* __restrict__ ws) {
    const unsigned short* L0p = (const unsigned short*)(ws + L0_B);
    int t = blockIdx.x * 256 + threadIdx.x;
    int l, tl;
    if (t < NP1)             { l = 1; tl = t; }
    else if (t < NP1 + NP2)  { l = 2; tl = t - NP1; }
    else                     { l = 3; tl = t - NP1 - NP2; }
    int Wo = W >> l, Ho = H >> l, S = 1 << l;
    int c2 = tl & 127;
    int r = tl >> 7;
    int x = r % Wo; r /= Wo;
    int y = r % Ho;
    int b = r / Ho;
    const unsigned short* src =
        L0p + ((size_t)(b * H + y * S) * W + x * S) * 128 + c2;
    int sx = 0, sy = 0;
    if (l == 1)      pool_accum<2>(src, sx, sy);
    else if (l == 2) pool_accum<4>(src, sx, sy);
    else             pool_accum<8>(src, sx, sy);
    float inv = 1.0f / (S * S);
    unsigned short* dst = (unsigned short*)(ws + (l == 1 ? L1_B : (l == 2 ? L2_B : L3_B)));
    dst[tl] = pack_i8x2((float)sx * inv, (float)sy * inv);
}

// ---------------------------------------------------------------------------
// corr_fused: block = (one pyramid level, 16 consecutive queries).
// 4 waves x 4 queries, processed as 2 INTERLEAVED PAIRS (two independent
// dep chains per inner iteration). 4 lanes per position, coalesced chunk
// order (instruction k = one 64-B line per position). Clamped loads + vmask.
// [r6/r10-verified: best measured corr, 53.3-54.7 us]
constexpr int QB = 672;                    // B*HW/16 query-groups per level
__global__ __launch_bounds__(256, 4) void corr_fused(
    const float* __restrict__ coords, const char* __restrict__ ws,
    float* __restrict__ out0) {
    __shared__ float Dsh[16][101];   // stride 101: conflict-free reads
    __shared__ float Wxy[16][2];

    int tid = threadIdx.x;
    int wave = tid >> 6;
    int lane = tid & 63;
    int v = lane & 3;              // 16-B sub-chunk within each 64-B line
    int grp = lane >> 2;           // position index within iteration, 0..15

    int bid = blockIdx.x;
    int l = bid / QB;              // level: blocks grouped by level
    int qb = bid - l * QB;
    int g0 = qb * 16;              // 16 consecutive flat queries
    int b = g0 / HW;
    int hw0 = g0 - b * HW;

    int Hl = H >> l, Wl = W >> l;
    int Wlm1 = Wl - 1, Hlm1 = Hl - 1;
    size_t off = (l == 0 ? L0_B : (l == 1 ? L1_B : (l == 2 ? L2_B : L3_B)));
    const char* base8 = ws + off + (size_t)b * Hl * Wl * C;
    float scale = (l == 0 ? 1.0f : (l == 1 ? 0.5f : (l == 2 ? 0.25f : 0.125f)));

    // p = it*16 + grp; (xo,yo) = (p%10, p/10); advance p+=16: xo+=6 mod 10.
    int xo0 = grp < 10 ? grp : grp - 10;
    int yo0 = grp < 10 ? 0 : 1;

    const char* f1b = ws + F1T_B;

#pragma unroll 1
    for (int pi = 0; pi < 2; ++pi) {
        int wqa = wave * 4 + pi * 2;     // query slots (pair)
        int wqb = wqa + 1;
        int ga = g0 + wqa, gb = g0 + wqb;

        // A fragments for both queries (chunk k at k*64 + v*16)
        const char* aba = f1b + (size_t)ga * C + (v << 4);
        const char* abb = f1b + (size_t)gb * C + (v << 4);
        int4 Aa0 = *(const int4*)(aba);
        int4 Aa1 = *(const int4*)(aba + 64);
        int4 Aa2 = *(const int4*)(aba + 128);
        int4 Aa3 = *(const int4*)(aba + 192);
        int4 Ab0 = *(const int4*)(abb);
        int4 Ab1 = *(const int4*)(abb + 64);
        int4 Ab2 = *(const int4*)(abb + 128);
        int4 Ab3 = *(const int4*)(abb + 192);

        float cxa = coords[(size_t)(b * 2 + 0) * HW + hw0 + wqa];
        float cya = coords[(size_t)(b * 2 + 1) * HW + hw0 + wqa];
        float cxb = coords[(size_t)(b * 2 + 0) * HW + hw0 + wqb];
        float cyb = coords[(size_t)(b * 2 + 1) * HW + hw0 + wqb];
        float fxa = cxa * scale, fya = cya * scale;
        float fxb = cxb * scale, fyb = cyb * scale;
        float fxfa = floorf(fxa), fyfa = floorf(fya);
        float fxfb = floorf(fxb), fyfb = floorf(fyb);
        int ixa = (int)fxfa, iya = (int)fyfa;
        int ixb = (int)fxfb, iyb = (int)fyfb;
        if (lane == 0) {
            Wxy[wqa][0] = fxa - fxfa; Wxy[wqa][1] = fya - fyfa;
            Wxy[wqb][0] = fxb - fxfb; Wxy[wqb][1] = fyb - fyfb;
        }

        // Precompute clamped byte offsets + validity (shared xo/yo walk)
        int offa[7], offb[7];
        unsigned mska = 0, mskb = 0;
        {
            int xo = xo0, yo = yo0;
#pragma unroll
            for (int it = 0; it < 7; ++it) {
                int xa = ixa - RADIUS + xo, ya = iya - RADIUS + yo;
                int xb = ixb - RADIUS + xo, yb = iyb - RADIUS + yo;
                if (((unsigned)xa < (unsigned)Wl) & ((unsigned)ya < (unsigned)Hl))
                    mska |= 1u << it;
                if (((unsigned)xb < (unsigned)Wl) & ((unsigned)yb < (unsigned)Hl))
                    mskb |= 1u << it;
                int xca = min(max(xa, 0), Wlm1), yca = min(max(ya, 0), Hlm1);
                int xcb = min(max(xb, 0), Wlm1), ycb = min(max(yb, 0), Hlm1);
                offa[it] = ((yca * Wl + xca) << 8) + (v << 4);
                offb[it] = ((ycb * Wl + xcb) << 8) + (v << 4);
                xo += 6;
                int cr = xo >= 10;
                xo -= cr ? 10 : 0;
                yo += 1 + cr;
            }
        }

#pragma unroll
        for (int it = 0; it < 7; ++it) {
            // issue BOTH queries' load batches up front
            int4 ca0 = *(const int4*)(base8 + offa[it]);
            int4 ca1 = *(const int4*)(base8 + offa[it] + 64);
            int4 ca2 = *(const int4*)(base8 + offa[it] + 128);
            int4 ca3 = *(const int4*)(base8 + offa[it] + 192);
            int4 cb0 = *(const int4*)(base8 + offb[it]);
            int4 cb1 = *(const int4*)(base8 + offb[it] + 64);
            int4 cb2 = *(const int4*)(base8 + offb[it] + 128);
            int4 cb3 = *(const int4*)(base8 + offb[it] + 192);

            // dots for query a (covers query b's loads in flight)
            int sa0 = 0, sa1 = 0, sa2 = 0, sa3 = 0;
            sa0 = dot4acc(ca0.x, Aa0.x, sa0); sa1 = dot4acc(ca0.y, Aa0.y, sa1);
            sa2 = dot4acc(ca0.z, Aa0.z, sa2); sa3 = dot4acc(ca0.w, Aa0.w, sa3);
            sa0 = dot4acc(ca1.x, Aa1.x, sa0); sa1 = dot4acc(ca1.y, Aa1.y, sa1);
            sa2 = dot4acc(ca1.z, Aa1.z, sa2); sa3 = dot4acc(ca1.w, Aa1.w, sa3);
            sa0 = dot4acc(ca2.x, Aa2.x, sa0); sa1 = dot4acc(ca2.y, Aa2.y, sa1);
            sa2 = dot4acc(ca2.z, Aa2.z, sa2); sa3 = dot4acc(ca2.w, Aa2.w, sa3);
            sa0 = dot4acc(ca3.x, Aa3.x, sa0); sa1 = dot4acc(ca3.y, Aa3.y, sa1);
            sa2 = dot4acc(ca3.z, Aa3.z, sa2); sa3 = dot4acc(ca3.w, Aa3.w, sa3);
            int sa = (sa0 + sa1) + (sa2 + sa3);
            sa = ((mska >> it) & 1) ? sa : 0;

            // dots for query b
            int sb0 = 0, sb1 = 0, sb2 = 0, sb3 = 0;
            sb0 = dot4acc(cb0.x, Ab0.x, sb0); sb1 = dot4acc(cb0.y, Ab0.y, sb1);
            sb2 = dot4acc(cb0.z, Ab0.z, sb2); sb3 = dot4acc(cb0.w, Ab0.w, sb3);
            sb0 = dot4acc(cb1.x, Ab1.x, sb0); sb1 = dot4acc(cb1.y, Ab1.y, sb1);
            sb2 = dot4acc(cb1.z, Ab1.z, sb2); sb3 = dot4acc(cb1.w, Ab1.w, sb3);
            sb0 = dot4acc(cb2.x, Ab2.x, sb0); sb1 = dot4acc(cb2.y, Ab2.y, sb1);
            sb2 = dot4acc(cb2.z, Ab2.z, sb2); sb3 = dot4acc(cb2.w, Ab2.w, sb3);
            sb0 = dot4acc(cb3.x, Ab3.x, sb0); sb1 = dot4acc(cb3.y, Ab3.y, sb1);
            sb2 = dot4acc(cb3.z, Ab3.z, sb2); sb3 = dot4acc(cb3.w, Ab3.w, sb3);
            int sb = (sb0 + sb1) + (sb2 + sb3);
            sb = ((mskb >> it) & 1) ? sb : 0;

            sa += __shfl_xor(sa, 1);
            sa += __shfl_xor(sa, 2);
            sb += __shfl_xor(sb, 1);
            sb += __shfl_xor(sb, 2);
            bool live = (it < 6) | (grp < 4);      // p < 100
            if (v == 0 && live) {
                Dsh[wqa][it * 16 + grp] = (float)sa * SCL;
                Dsh[wqb][it * 16 + grp] = (float)sb * SCL;
            }
        }
    }
    __syncthreads();

    // Bilinear combine + [B,324,HW] f32 write: 16 q x 4 B = full 64-B lines
    int chbase = l * 81;
    for (int o = tid; o < 81 * 16; o += 256) {
        int q = o & 15, ch = o >> 4;
        int xo = ch / 9;                       // x-offset slow (reference quirk)
        int yo = ch - xo * 9;                  // y-offset fast
        float wxv = Wxy[q][0], wyv = Wxy[q][1];
        const float* D = Dsh[q];
        float v00 = D[yo * 10 + xo];
        float v01 = D[yo * 10 + xo + 1];
        float v10 = D[yo * 10 + xo + 10];
        float v11 = D[yo * 10 + xo + 11];
        float res = (1.f - wyv) * ((1.f - wxv) * v00 + wxv * v01)
                  +        wyv  * ((1.f - wxv) * v10 + wxv * v11);
        out0[((size_t)(b * 324 + chbase + ch)) * HW + hw0 + q] = res;
    }
}

extern "C" void kernel_launch(void* const* d_in, const int* in_sizes, int n_in,
                              void* d_out, int out_size, void* d_ws, size_t ws_size,
                              hipStream_t stream) {
    const float* fmap1  = (const float*)d_in[0];
    const float* fmap2  = (const float*)d_in[1];
    const float* coords = (const float*)d_in[2];
    const float* flow   = (const float*)d_in[3];
    const float* maskp  = (const float*)d_in[4];
    float* out = (float*)d_out;
    char* ws = (char*)d_ws;

    prep_kernel<<<TP_BLOCKS + CU_BLOCKS, 256, 0, stream>>>(
        fmap1, fmap2, flow, maskp, ws, out + OUT0_ELEMS);
    build_pools<<<(NP1 + NP2 + NP3) / 256, 256, 0, stream>>>(ws);
    corr_fused<<<4 * QB, 256, 0, stream>>>(coords, ws, out);
}